// Round 10
// baseline (672.531 us; speedup 1.0000x reference)
//
#include <hip/hip_runtime.h>

#define NTOK  384
#define SPANS 73920          // 384*385/2
#define MTILES 584           // 73*8 so grid=584*8 maps cleanly onto 8 XCDs
#define MPAD  (MTILES * 128) // 74752
#define HD    1024
#define BK    32
#define KTS   (HD / BK)      // 32
#define YSLICE ((size_t)NTOK * HD)

typedef unsigned short u16;
typedef __attribute__((ext_vector_type(8))) short short8;
typedef __attribute__((ext_vector_type(4))) float floatx4;

// gfx9 s_waitcnt immediate: vmcnt[3:0]|[15:14], expcnt[6:4], lgkmcnt[11:8]
#define VMCNT_IMM(N) (((N) & 0xF) | (((N) >> 4) << 14) | (0x7 << 4) | (0xF << 8))

__device__ __forceinline__ u16 f2bu(float x) {
  union { float f; unsigned u; } un; un.f = x;
  unsigned r = un.u + 0x7fffu + ((un.u >> 16) & 1u);   // RNE
  return (u16)(r >> 16);
}

__device__ __forceinline__ void gld_lds16(const void* g, void* l) {
  __builtin_amdgcn_global_load_lds(
      (const __attribute__((address_space(1))) void*)g,
      (__attribute__((address_space(3))) void*)l, 16, 0, 0);
}

// ---- fused prep: castT (3072 blocks) | emb_gather (384) | spans (292) | svec (4) ----
__global__ void prep_misc(const int* __restrict__ sent, const int* __restrict__ pos,
                          const float* __restrict__ Wwrd, const float* __restrict__ Wpos,
                          u16* __restrict__ embB,
                          int* __restrict__ spI, int* __restrict__ spE, float* __restrict__ spInv,
                          float* __restrict__ scores, const float* __restrict__ bs2,
                          const float* __restrict__ Wd1, const float* __restrict__ Wd2,
                          const float* __restrict__ Ws1,
                          u16* __restrict__ o1, u16* __restrict__ o2, u16* __restrict__ o3,
                          float* __restrict__ S0, float* __restrict__ S1v, float* __restrict__ S2v) {
  __shared__ u16 tile[32][33];
  int bx = blockIdx.x;
  if (bx < 3072) {
    // transpose+cast the three 1024x1024 weight blocks to bf16 B^T [N][K]
    int w = bx >> 10, rem = bx & 1023;
    int tk = rem >> 5, tn = rem & 31;
    const float* src = (w == 0) ? Wd1 : ((w == 1) ? Wd2 : Ws1);
    u16* dst = (w == 0) ? o1 : ((w == 1) ? o2 : o3);
    int x = threadIdx.x & 31, y = threadIdx.x >> 5;   // y in 0..7
    int k0 = tk * 32, n0 = tn * 32;
    for (int yy = 0; yy < 32; yy += 8)
      tile[y + yy][x] = f2bu(src[(size_t)(k0 + y + yy) * HD + n0 + x]);
    __syncthreads();
    for (int yy = 0; yy < 32; yy += 8)
      dst[(size_t)(n0 + y + yy) * HD + k0 + x] = tile[x][y + yy];
  } else if (bx < 3072 + NTOK) {
    // gather token embeddings as bf16 [384][1024]
    int t = bx - 3072;
    int c = threadIdx.x;
    int pt = pos[t], st = sent[t];
    #pragma unroll
    for (int u = 0; u < 4; ++u) {
      int col = u * 256 + c;
      float v = (col < 512) ? Wpos[(size_t)pt * 512 + col]
                            : Wwrd[(size_t)st * 512 + (col - 512)];
      embB[(size_t)t * HD + col] = f2bu(v);
    }
  } else if (bx < 3072 + NTOK + 292) {
    // span (i, end, 1/len) + scores init
    int rf = (bx - 3072 - NTOK) * 256 + threadIdx.x;
    if (rf >= MPAD) return;
    int s = rf < SPANS ? rf : SPANS - 1;
    const int n = NTOK;
    double tn2 = 2.0 * n + 1.0;
    int i = (int)((tn2 - sqrt(tn2 * tn2 - 8.0 * (double)s)) * 0.5);
    if (i < 0) i = 0;
    if (i > n - 1) i = n - 1;
    #define OFF(ii) (((ii) * (2 * n - (ii) + 1)) / 2)
    while (i + 1 <= n - 1 && OFF(i + 1) <= s) ++i;
    while (i > 0 && OFF(i) > s) --i;
    int j = i + (s - OFF(i));
    #undef OFF
    spI[rf] = i;
    spE[rf] = j + 1;
    spInv[rf] = 1.0f / (float)(j + 1 - i);
    if (rf < SPANS) scores[rf] = bs2[0];
  } else {
    // S0/S1/S2 = column sums of W_s1's feat rows (len/start/end, 16 each)
    int c = (bx - 3072 - NTOK - 292) * 256 + threadIdx.x;
    if (c >= HD) return;
    float a = 0.f, b = 0.f, d = 0.f;
    for (int r = 0; r < 16; ++r) {
      a += Ws1[(size_t)(1024 + r) * HD + c];
      b += Ws1[(size_t)(1040 + r) * HD + c];
      d += Ws1[(size_t)(1056 + r) * HD + c];
    }
    S0[c] = a; S1v[c] = b; S2v[c] = d;
  }
}

// ---- reshuffle B^T -> fragment-major layout [nt][kt][wn][ni][lane]x16B.
// Lane (q=lane>>4, r=lane&15) slot holds Bt[nt*128 + wn*64 + ni*16 + r][kt*32 + q*8 .. +7]
__global__ void bfrag(const u16* __restrict__ t1, const u16* __restrict__ t2, const u16* __restrict__ t3,
                      u16* __restrict__ f1, u16* __restrict__ f2, u16* __restrict__ f3) {
  int b = blockIdx.x;            // 3*1024: w | nt(0..7) | kt(0..31)
  int w = b >> 10, rem = b & 1023;
  int nt = rem >> 5, kt = rem & 31;
  const u16* src = (w == 0) ? t1 : ((w == 1) ? t2 : t3);
  u16* dst = (w == 0) ? f1 : ((w == 1) ? f2 : f3);
  int t = threadIdx.x;
  int ni = t >> 6, lane = t & 63, q = lane >> 4, r = lane & 15;
  #pragma unroll
  for (int wn = 0; wn < 2; ++wn) {
    const u16* s = src + (size_t)(nt * 128 + wn * 64 + ni * 16 + r) * HD + kt * 32 + q * 8;
    u16* d = dst + (size_t)nt * 131072 + kt * 4096 + wn * 2048 + ni * 512 + lane * 8;
    *(short8*)d = *(const short8*)s;
  }
}

// ---- Qp = [0; cumsum(sum of 4 K-partials, rows)] fp32, per-column parallel scan ----
__global__ void yscan(const float* __restrict__ Y, float* __restrict__ Qp) {
  __shared__ float buf[NTOK];
  int c = blockIdx.x;           // 0..1023
  int t = threadIdx.x;          // 0..383
  size_t idx = (size_t)t * HD + c;
  buf[t] = Y[idx] + Y[idx + YSLICE] + Y[idx + 2 * YSLICE] + Y[idx + 3 * YSLICE];
  __syncthreads();
  #pragma unroll
  for (int off = 1; off < NTOK; off <<= 1) {
    float add = (t >= off) ? buf[t - off] : 0.f;
    __syncthreads();
    buf[t] += add;
    __syncthreads();
  }
  if (t == 0) Qp[c] = 0.f;
  Qp[(size_t)(t + 1) * HD + c] = buf[t];
}

// ---- expand: h1[s] = relu((Qp[e]-Qp[i])*inv + b1) -> bf16, FRAGMENT-MAJOR ----
// AF(row,col): mt=row>>7, wm=(row>>6)&1, x=(row>>4)&3, r=row&15, kt=col>>5,
// q=(col>>3)&3, lane=q*16+r; addr = (((mt*32+kt)*2+wm)*4+x)*512 + lane*8 + (col&7).
// Thread still writes one contiguous uint4 (8 cols of one row).
__global__ void expand(const float* __restrict__ Qp, const int* __restrict__ spI,
                       const int* __restrict__ spE, const float* __restrict__ spInv,
                       const float* __restrict__ b1, u16* __restrict__ out) {
  int gid = blockIdx.x * 256 + threadIdx.x;   // MPAD*128 threads
  int row = gid >> 7;
  int c0 = (gid & 127) << 3;
  int i = spI[row], e = spE[row];
  float inv = spInv[row];
  const float* pe = Qp + (size_t)e * HD + c0;
  const float* pi = Qp + (size_t)i * HD + c0;
  const float* bb = b1 + c0;
  u16 tmp[8];
  #pragma unroll
  for (int u = 0; u < 8; ++u) {
    float v = (pe[u] - pi[u]) * inv + bb[u];
    v = v > 0.f ? v : 0.f;
    tmp[u] = f2bu(v);
  }
  int mt = row >> 7, wm = (row >> 6) & 1, x = (row >> 4) & 3, r = row & 15;
  int kt = c0 >> 5, q = (c0 >> 3) & 3;
  size_t addr = (((size_t)(mt * 32 + kt) * 2 + wm) * 4 + x) * 512 + (q * 16 + r) * 8;
  *(uint4*)(out + addr) = *(const uint4*)tmp;
}

// ---- small Y-GEMM (split-K x4, 96 blocks), R9-verified structure:
// A (embB, row-major) via LDS stripe staging; B from fragment-major Wd1f. ----
__global__ __launch_bounds__(256, 3) void gemm_y(
    const u16* __restrict__ A, const u16* __restrict__ Bf, float* __restrict__ Cf) {
  __shared__ u16 As[2][128 * BK];
  int bx = blockIdx.x;
  int rem = bx & 31;
  int nt = rem & 7, ks = rem >> 3, mt = bx >> 5;   // grid 96 = 3mt x 8nt x 4ks
  int KT0 = ks * 8, KT1 = KT0 + 8;
  int m0 = mt * 128, n0 = nt * 128;
  int t = threadIdx.x, lane = t & 63, wid = t >> 6;
  int wm = wid >> 1, wn = wid & 1;
  int q = lane >> 4, r = lane & 15;

  floatx4 acc[4][4] = {};

  int dsub = (lane & 7) ^ ((lane >> 3) & 7);
  int row0 = wid * 16 + 2 * (lane >> 3) + (dsub >> 2);
  int voff = row0 * HD + (dsub & 3) * 8;
  const u16* gA0 = A + (size_t)m0 * HD;
  int ldsOff0 = wid * 512;
  int ldsOff1 = 2048 + wid * 512;

  auto stageA = [&](int kt, int b) {
    const u16* pa = gA0 + voff + kt * BK;
    gld_lds16(pa,                   &As[b][ldsOff0]);
    gld_lds16(pa + (size_t)64 * HD, &As[b][ldsOff1]);
  };

  const u16* gBb = Bf + (size_t)nt * 131072 + wn * 2048 + lane * 8;
  auto loadB = [&](int kt, short8 (&bf)[4]) {
    #pragma unroll
    for (int ni = 0; ni < 4; ++ni)
      bf[ni] = *(const short8*)(gBb + (size_t)kt * 4096 + ni * 512);
  };

  int oct = (((r & 1) << 2) + q) ^ ((r >> 1) & 7);
  int aoff[4];
  #pragma unroll
  for (int x = 0; x < 4; ++x)
    aoff[x] = (wm * 32 + x * 8 + (r >> 1)) * 64 + oct * 8;

  short8 af[4], bfA[4], bfB[4];
  auto preloadA = [&](int b) {
    #pragma unroll
    for (int x = 0; x < 4; ++x) af[x] = *(const short8*)(&As[b][aoff[x]]);
  };
  auto burst = [&](short8 (&bf)[4]) {
    #pragma unroll
    for (int ni = 0; ni < 4; ++ni)
      #pragma unroll
      for (int mi = 0; mi < 4; ++mi)
        acc[mi][ni] = __builtin_amdgcn_mfma_f32_16x16x32_bf16(af[mi], bf[ni], acc[mi][ni], 0, 0, 0);
  };

  stageA(KT0, 0);
  stageA(KT0 + 1, 1);
  loadB(KT0, bfA);
  loadB(KT0 + 1, bfB);
  __builtin_amdgcn_s_waitcnt(VMCNT_IMM(0));
  __builtin_amdgcn_s_barrier();
  preloadA(0);

  #pragma unroll 1
  for (int kt = KT0; kt < KT1; kt += 2) {
    burst(bfA);
    __builtin_amdgcn_s_waitcnt(VMCNT_IMM(0));
    __builtin_amdgcn_s_barrier();
    if (kt + 2 < KT1) { stageA(kt + 2, 0); loadB(kt + 2, bfA); }
    preloadA(1);
    burst(bfB);
    __builtin_amdgcn_s_waitcnt(VMCNT_IMM(0));
    __builtin_amdgcn_s_barrier();
    if (kt + 3 < KT1) { stageA(kt + 3, 1); loadB(kt + 3, bfB); }
    if (kt + 2 < KT1) preloadA(0);
  }

  float* Cfk = Cf + (size_t)ks * YSLICE;
  #pragma unroll
  for (int mi = 0; mi < 4; ++mi) {
    int rowb = m0 + wm * 64 + mi * 16 + q * 4;
    #pragma unroll
    for (int ni = 0; ni < 4; ++ni) {
      int col = n0 + wn * 64 + ni * 16 + r;
      #pragma unroll
      for (int e = 0; e < 4; ++e)
        Cfk[(size_t)(rowb + e) * HD + col] = acc[mi][ni][e];
    }
  }
}

// ---- big GEMM, Round-10: ZERO-barrier, ZERO-LDS fragment GEMM.
// Both A and B live in fragment-major global layout (L2/L3-resident, perfectly
// coalesced 1KB/instr loads straight to registers). Per K-step: 4 A-frag + 4
// B-frag loads (double-buffered named regs, static indexing) + 16 MFMA. Waves
// run fully independent — no rendezvous, latency hidden by wave drift + MFMA.
// EPI==0: relu+bias, store bf16 C in FRAGMENT-MAJOR (feeds next gemm_nf as A).
// EPI==1: + feats affine, relu, dot W_s2, shfl reduce, atomicAdd scores.
template <int EPI>
__global__ __launch_bounds__(256, 3) void gemm_nf(
    const u16* __restrict__ Af, const u16* __restrict__ Bf,
    const float* __restrict__ bias, u16* __restrict__ Cf,
    const int* __restrict__ spI, const int* __restrict__ spE,
    const float* __restrict__ S0, const float* __restrict__ S1v, const float* __restrict__ S2v,
    const float* __restrict__ Ws2, float* __restrict__ scores) {
  int bx = blockIdx.x;
  int xcd = bx & 7, k = bx >> 3;
  int nt = k & 7;
  int mt = xcd + 8 * (k >> 3);      // mt%8 == xcd; blocks per XCD share mt (A L2 reuse)
  int t = threadIdx.x, lane = t & 63, wid = t >> 6;
  int wm = wid >> 1, wn = wid & 1;
  int q = lane >> 4, r = lane & 15;

  floatx4 acc[4][4] = {};

  const u16* gA = Af + (size_t)mt * 131072 + wm * 2048 + lane * 8;
  const u16* gB = Bf + (size_t)nt * 131072 + wn * 2048 + lane * 8;

  short8 afA[4], afB[4], bfA[4], bfB[4];
  auto loadA = [&](int kt, short8 (&af)[4]) {
    #pragma unroll
    for (int x = 0; x < 4; ++x) af[x] = *(const short8*)(gA + (size_t)kt * 4096 + x * 512);
  };
  auto loadB = [&](int kt, short8 (&bf)[4]) {
    #pragma unroll
    for (int ni = 0; ni < 4; ++ni) bf[ni] = *(const short8*)(gB + (size_t)kt * 4096 + ni * 512);
  };
  auto burst = [&](short8 (&af)[4], short8 (&bf)[4]) {
    #pragma unroll
    for (int ni = 0; ni < 4; ++ni)
      #pragma unroll
      for (int mi = 0; mi < 4; ++mi)
        acc[mi][ni] = __builtin_amdgcn_mfma_f32_16x16x32_bf16(af[mi], bf[ni], acc[mi][ni], 0, 0, 0);
  };

  loadA(0, afA); loadB(0, bfA);
  loadA(1, afB); loadB(1, bfB);
  #pragma unroll 1
  for (int kt = 0; kt < KTS; kt += 2) {
    burst(afA, bfA);                                     // waits kt's 8 loads (reg deps)
    if (kt + 2 < KTS) { loadA(kt + 2, afA); loadB(kt + 2, bfA); }
    burst(afB, bfB);                                     // kt+1's loads: issued 1 burst ago
    if (kt + 3 < KTS) { loadA(kt + 3, afB); loadB(kt + 3, bfB); }
  }

  if (EPI == 0) {
    // store C in fragment-major: value at (row,col) ->
    // slab = ((mt*32 + nt*4 + wn*2 + (ni>>1))*2 + wm)*4 + mi;  lane2 = q2*16 + q*4 + e
    // q2 = (ni&1)*2 + (r>>3);  u2 = r&7
    #pragma unroll
    for (int ni = 0; ni < 4; ++ni) {
      int col = nt * 128 + wn * 64 + ni * 16 + r;
      float bcol = bias[col];
      int q2 = (ni & 1) * 2 + (r >> 3);
      #pragma unroll
      for (int mi = 0; mi < 4; ++mi) {
        size_t slab = ((size_t)(mt * 32 + nt * 4 + wn * 2 + (ni >> 1)) * 2 + wm) * 4 + mi;
        u16* base = Cf + slab * 512 + (size_t)(q2 * 16 + q * 4) * 8 + (r & 7);
        #pragma unroll
        for (int e = 0; e < 4; ++e) {
          float v = acc[mi][ni][e] + bcol;
          v = v > 0.f ? v : 0.f;
          base[e * 8] = f2bu(v);
        }
      }
    }
  } else {
    float bcol[4], s0c[4], s1c[4], s2c[4], wsc[4];
    #pragma unroll
    for (int ni = 0; ni < 4; ++ni) {
      int col = nt * 128 + wn * 64 + ni * 16 + r;
      bcol[ni] = bias[col]; s0c[ni] = S0[col]; s1c[ni] = S1v[col];
      s2c[ni] = S2v[col];  wsc[ni] = Ws2[col];
    }
    int m0 = mt * 128;
    #pragma unroll
    for (int mi = 0; mi < 4; ++mi) {
      int rowb = m0 + wm * 64 + mi * 16 + q * 4;
      #pragma unroll
      for (int e = 0; e < 4; ++e) {
        int row = rowb + e;
        float fi = (float)spI[row];
        float fe = (float)spE[row];
        float fl = fe - fi;
        float p = 0.f;
        #pragma unroll
        for (int ni = 0; ni < 4; ++ni) {
          float v = acc[mi][ni][e] + bcol[ni] + fl * s0c[ni] + fi * s1c[ni] + fe * s2c[ni];
          v = v > 0.f ? v : 0.f;
          p += v * wsc[ni];
        }
        p += __shfl_xor(p, 1);
        p += __shfl_xor(p, 2);
        p += __shfl_xor(p, 4);
        p += __shfl_xor(p, 8);
        if (r == 0 && row < SPANS) atomicAdd(&scores[row], p);
      }
    }
  }
}

extern "C" void kernel_launch(void* const* d_in, const int* in_sizes, int n_in,
                              void* d_out, int out_size, void* d_ws, size_t ws_size,
                              hipStream_t stream) {
  const int*   sent = (const int*)d_in[0];
  const int*   pos  = (const int*)d_in[1];
  const float* Wwrd = (const float*)d_in[2];
  const float* Wpos = (const float*)d_in[3];
  const float* Wd1  = (const float*)d_in[4];
  const float* bd1  = (const float*)d_in[5];
  const float* Wd2  = (const float*)d_in[6];
  const float* bd2  = (const float*)d_in[7];
  const float* Ws1  = (const float*)d_in[8];
  const float* bs1  = (const float*)d_in[9];
  const float* Ws2  = (const float*)d_in[10];
  const float* bs2  = (const float*)d_in[11];
  float* scores = (float*)d_out;

  char* w = (char*)d_ws;
  size_t o = 0;
  auto alloc = [&](size_t bytes) {
    char* p = w + o;
    o = (o + bytes + 255) & ~(size_t)255;
    return p;
  };
  int*   spI   = (int*)  alloc((size_t)MPAD * 4);
  int*   spE   = (int*)  alloc((size_t)MPAD * 4);
  float* spInv = (float*)alloc((size_t)MPAD * 4);
  float* S0    = (float*)alloc(4096);
  float* S1v   = (float*)alloc(4096);
  float* S2v   = (float*)alloc(4096);
  u16*   embB  = (u16*)  alloc((size_t)NTOK * HD * 2);
  float* Ybuf  = (float*)alloc(4 * YSLICE * 4);      // 4 split-K partials
  float* Qp    = (float*)alloc((size_t)(NTOK + 1) * HD * 4);
  u16* Wd1t = (u16*)alloc((size_t)HD * HD * 2);
  u16* Wd2t = (u16*)alloc((size_t)HD * HD * 2);
  u16* Ws1t = (u16*)alloc((size_t)HD * HD * 2);
  u16* Wd1f = (u16*)alloc((size_t)HD * HD * 2);      // fragment-major B buffers
  u16* Wd2f = (u16*)alloc((size_t)HD * HD * 2);
  u16* Ws1f = (u16*)alloc((size_t)HD * HD * 2);
  u16* bufA = (u16*)alloc((size_t)MPAD * HD * 2);    // fragment-major A buffers
  u16* bufB = (u16*)alloc((size_t)MPAD * HD * 2);

  // fused prep: castT | emb_gather | spans+scores-init | svec
  prep_misc<<<3072 + NTOK + 292 + 4, 256, 0, stream>>>(
      sent, pos, Wwrd, Wpos, embB,
      spI, spE, spInv, scores, bs2,
      Wd1, Wd2, Ws1, Wd1t, Wd2t, Ws1t,
      S0, S1v, S2v);
  // reshuffle B^T -> fragment-major
  bfrag<<<3072, 256, 0, stream>>>(Wd1t, Wd2t, Ws1t, Wd1f, Wd2f, Ws1f);

  // Y = emb @ Wd1  (384x1024x1024, split-K x4 -> 96 blocks, fp32 partials)
  gemm_y<<<96, 256, 0, stream>>>(embB, Wd1f, Ybuf);
  yscan<<<HD, NTOK, 0, stream>>>(Ybuf, Qp);
  expand<<<MPAD / 2, 256, 0, stream>>>(Qp, spI, spE, spInv, bd1, bufA);

  gemm_nf<0><<<MTILES * 8, 256, 0, stream>>>(bufA, Wd2f, bd2, bufB,
                                             nullptr, nullptr, nullptr, nullptr, nullptr,
                                             nullptr, nullptr);
  gemm_nf<1><<<MTILES * 8, 256, 0, stream>>>(bufB, Ws1f, bs1, nullptr,
                                             spI, spE, S0, S1v, S2v, Ws2, scores);
}

// Round 11
// 577.673 us; speedup vs baseline: 1.1642x; 1.1642x over previous
//
#include <hip/hip_runtime.h>

#define NTOK  384
#define SPANS 73920          // 384*385/2
#define MTILES 584           // 73*8 so grid=584*8 maps cleanly onto 8 XCDs
#define MPAD  (MTILES * 128) // 74752
#define HD    1024
#define BK    32
#define KTS   (HD / BK)      // 32
#define YSLICE ((size_t)NTOK * HD)

typedef unsigned short u16;
typedef __attribute__((ext_vector_type(8))) short short8;
typedef __attribute__((ext_vector_type(4))) float floatx4;

// gfx9 s_waitcnt immediate: vmcnt[3:0]|[15:14], expcnt[6:4], lgkmcnt[11:8]
#define VMCNT_IMM(N) (((N) & 0xF) | (((N) >> 4) << 14) | (0x7 << 4) | (0xF << 8))

__device__ __forceinline__ u16 f2bu(float x) {
  union { float f; unsigned u; } un; un.f = x;
  unsigned r = un.u + 0x7fffu + ((un.u >> 16) & 1u);   // RNE
  return (u16)(r >> 16);
}

__device__ __forceinline__ void gld_lds16(const void* g, void* l) {
  __builtin_amdgcn_global_load_lds(
      (const __attribute__((address_space(1))) void*)g,
      (__attribute__((address_space(3))) void*)l, 16, 0, 0);
}

// ---- fused prep: castT (3072 blocks) | emb_gather (384) | spans (292) | svec (4) ----
__global__ void prep_misc(const int* __restrict__ sent, const int* __restrict__ pos,
                          const float* __restrict__ Wwrd, const float* __restrict__ Wpos,
                          u16* __restrict__ embB,
                          int* __restrict__ spI, int* __restrict__ spE, float* __restrict__ spInv,
                          float* __restrict__ scores, const float* __restrict__ bs2,
                          const float* __restrict__ Wd1, const float* __restrict__ Wd2,
                          const float* __restrict__ Ws1,
                          u16* __restrict__ o1, u16* __restrict__ o2, u16* __restrict__ o3,
                          float* __restrict__ S0, float* __restrict__ S1v, float* __restrict__ S2v) {
  __shared__ u16 tile[32][33];
  int bx = blockIdx.x;
  if (bx < 3072) {
    // transpose+cast the three 1024x1024 weight blocks to bf16 B^T [N][K]
    int w = bx >> 10, rem = bx & 1023;
    int tk = rem >> 5, tn = rem & 31;
    const float* src = (w == 0) ? Wd1 : ((w == 1) ? Wd2 : Ws1);
    u16* dst = (w == 0) ? o1 : ((w == 1) ? o2 : o3);
    int x = threadIdx.x & 31, y = threadIdx.x >> 5;   // y in 0..7
    int k0 = tk * 32, n0 = tn * 32;
    for (int yy = 0; yy < 32; yy += 8)
      tile[y + yy][x] = f2bu(src[(size_t)(k0 + y + yy) * HD + n0 + x]);
    __syncthreads();
    for (int yy = 0; yy < 32; yy += 8)
      dst[(size_t)(n0 + y + yy) * HD + k0 + x] = tile[x][y + yy];
  } else if (bx < 3072 + NTOK) {
    // gather token embeddings as bf16 [384][1024]
    int t = bx - 3072;
    int c = threadIdx.x;
    int pt = pos[t], st = sent[t];
    #pragma unroll
    for (int u = 0; u < 4; ++u) {
      int col = u * 256 + c;
      float v = (col < 512) ? Wpos[(size_t)pt * 512 + col]
                            : Wwrd[(size_t)st * 512 + (col - 512)];
      embB[(size_t)t * HD + col] = f2bu(v);
    }
  } else if (bx < 3072 + NTOK + 292) {
    // span (i, end, 1/len) + scores init
    int rf = (bx - 3072 - NTOK) * 256 + threadIdx.x;
    if (rf >= MPAD) return;
    int s = rf < SPANS ? rf : SPANS - 1;
    const int n = NTOK;
    double tn2 = 2.0 * n + 1.0;
    int i = (int)((tn2 - sqrt(tn2 * tn2 - 8.0 * (double)s)) * 0.5);
    if (i < 0) i = 0;
    if (i > n - 1) i = n - 1;
    #define OFF(ii) (((ii) * (2 * n - (ii) + 1)) / 2)
    while (i + 1 <= n - 1 && OFF(i + 1) <= s) ++i;
    while (i > 0 && OFF(i) > s) --i;
    int j = i + (s - OFF(i));
    #undef OFF
    spI[rf] = i;
    spE[rf] = j + 1;
    spInv[rf] = 1.0f / (float)(j + 1 - i);
    if (rf < SPANS) scores[rf] = bs2[0];
  } else {
    // S0/S1/S2 = column sums of W_s1's feat rows (len/start/end, 16 each)
    int c = (bx - 3072 - NTOK - 292) * 256 + threadIdx.x;
    if (c >= HD) return;
    float a = 0.f, b = 0.f, d = 0.f;
    for (int r = 0; r < 16; ++r) {
      a += Ws1[(size_t)(1024 + r) * HD + c];
      b += Ws1[(size_t)(1040 + r) * HD + c];
      d += Ws1[(size_t)(1056 + r) * HD + c];
    }
    S0[c] = a; S1v[c] = b; S2v[c] = d;
  }
}

// ---- reshuffle B^T -> fragment-major layout [nt][kt][wn][ni][lane]x16B.
// Lane (q=lane>>4, r=lane&15) slot holds Bt[nt*128 + wn*64 + ni*16 + r][kt*32 + q*8 .. +7]
__global__ void bfrag(const u16* __restrict__ t1, const u16* __restrict__ t2, const u16* __restrict__ t3,
                      u16* __restrict__ f1, u16* __restrict__ f2, u16* __restrict__ f3) {
  int b = blockIdx.x;            // 3*1024: w | nt(0..7) | kt(0..31)
  int w = b >> 10, rem = b & 1023;
  int nt = rem >> 5, kt = rem & 31;
  const u16* src = (w == 0) ? t1 : ((w == 1) ? t2 : t3);
  u16* dst = (w == 0) ? f1 : ((w == 1) ? f2 : f3);
  int t = threadIdx.x;
  int ni = t >> 6, lane = t & 63, q = lane >> 4, r = lane & 15;
  #pragma unroll
  for (int wn = 0; wn < 2; ++wn) {
    const u16* s = src + (size_t)(nt * 128 + wn * 64 + ni * 16 + r) * HD + kt * 32 + q * 8;
    u16* d = dst + (size_t)nt * 131072 + kt * 4096 + wn * 2048 + ni * 512 + lane * 8;
    *(short8*)d = *(const short8*)s;
  }
}

// ---- Qp = [0; cumsum(sum of 4 K-partials, rows)] fp32, per-column parallel scan ----
__global__ void yscan(const float* __restrict__ Y, float* __restrict__ Qp) {
  __shared__ float buf[NTOK];
  int c = blockIdx.x;           // 0..1023
  int t = threadIdx.x;          // 0..383
  size_t idx = (size_t)t * HD + c;
  buf[t] = Y[idx] + Y[idx + YSLICE] + Y[idx + 2 * YSLICE] + Y[idx + 3 * YSLICE];
  __syncthreads();
  #pragma unroll
  for (int off = 1; off < NTOK; off <<= 1) {
    float add = (t >= off) ? buf[t - off] : 0.f;
    __syncthreads();
    buf[t] += add;
    __syncthreads();
  }
  if (t == 0) Qp[c] = 0.f;
  Qp[(size_t)(t + 1) * HD + c] = buf[t];
}

// ---- expand: h1[s] = relu((Qp[e]-Qp[i])*inv + b1) -> bf16 [MPAD][1024] (row-major) ----
__global__ void expand(const float* __restrict__ Qp, const int* __restrict__ spI,
                       const int* __restrict__ spE, const float* __restrict__ spInv,
                       const float* __restrict__ b1, u16* __restrict__ out) {
  int gid = blockIdx.x * 256 + threadIdx.x;   // MPAD*128 threads
  int row = gid >> 7;
  int c0 = (gid & 127) << 3;
  int i = spI[row], e = spE[row];
  float inv = spInv[row];
  const float* pe = Qp + (size_t)e * HD + c0;
  const float* pi = Qp + (size_t)i * HD + c0;
  const float* bb = b1 + c0;
  u16 tmp[8];
  #pragma unroll
  for (int u = 0; u < 8; ++u) {
    float v = (pe[u] - pi[u]) * inv + bb[u];
    v = v > 0.f ? v : 0.f;
    tmp[u] = f2bu(v);
  }
  *(uint4*)(out + (size_t)row * HD + c0) = *(const uint4*)tmp;
}

// ---- GEMM: C[M,1024] = A[M,1024] @ B^T (+ bias, relu)
// R9-verified structure: 128x128 tile, 4 waves, BK=32; A via gld_lds stripe
// staging; B direct from fragment-major global (L2-resident, coalesced) into
// named double-buffered registers.
// Round-11 change: A staging 2-slot ping-pong + vmcnt(0) -> 3-SLOT RING with
// counted vmcnt(6). Stage(kt+1) being certified at step kt was issued at step
// kt-2 (~2 K-steps, >1100 cyc in flight > L3 latency) -> never memory-stalls.
// vmcnt(6) leaves the newest prefetch bundle (4 B-loads + 2 A-stages) in
// flight; ledger verified for steady state, prologue (drain to 8), and tails.
// EPI==0: relu+bias, store bf16 C (row-major).
// EPI==1: + feats affine, relu, dot W_s2, shfl reduce, atomicAdd scores.
// EPI==2: plain fp32 store, split-K x4 (grid 96, 8 K-steps each).
template <int EPI>
__global__ __launch_bounds__(256, 4) void gemm_bt(
    const u16* __restrict__ A, const u16* __restrict__ Bf,
    const float* __restrict__ bias, u16* __restrict__ C, float* __restrict__ Cf,
    const int* __restrict__ spI, const int* __restrict__ spE,
    const float* __restrict__ S0, const float* __restrict__ S1v, const float* __restrict__ S2v,
    const float* __restrict__ Ws2, float* __restrict__ scores) {
  __shared__ u16 As[3][128 * BK];   // 3 ring slots x 8 KB; A only
  int bx = blockIdx.x;
  int mt, nt, ks = 0, KT0 = 0, KT1 = KTS;
  if (EPI == 2) {
    int rem = bx & 31;
    nt = rem & 7; ks = rem >> 3; mt = bx >> 5;     // grid 96 = 3mt x 8nt x 4ks
    KT0 = ks * 8; KT1 = KT0 + 8;
  } else {
    int xcd = bx & 7, k = bx >> 3;
    nt = k & 7;
    mt = xcd + 8 * (k >> 3);        // mt%8 == xcd; blocks per XCD share mt (A L2 reuse)
  }
  int m0 = mt * 128;
  int n0 = nt * 128;
  int t = threadIdx.x, lane = t & 63, wid = t >> 6;
  int wm = wid >> 1, wn = wid & 1;
  int q = lane >> 4, r = lane & 15;

  floatx4 acc[4][4] = {};

  // ---- A staging geometry (verified stripe swizzle; one DMA op = 16 rows x 64B) ----
  int dsub = (lane & 7) ^ ((lane >> 3) & 7);
  int row0 = wid * 16 + 2 * (lane >> 3) + (dsub >> 2);
  int voff = row0 * HD + (dsub & 3) * 8;          // u16 elems; kt-invariant
  const u16* gA0 = A + (size_t)m0 * HD;
  int ldsOff0 = wid * 512;                        // u16; wave-uniform dests
  int ldsOff1 = 2048 + wid * 512;                 // +64 rows = +32 stripes

  auto stageA = [&](int kt, int sl) {
    const u16* pa = gA0 + voff + kt * BK;
    gld_lds16(pa,                   &As[sl][ldsOff0]);
    gld_lds16(pa + (size_t)64 * HD, &As[sl][ldsOff1]);
  };

  // ---- B fragment-major base (u16 units): nt*131072 + kt*4096 + wn*2048 + ni*512 + lane*8 ----
  const u16* gBb = Bf + (size_t)nt * 131072 + wn * 2048 + lane * 8;
  auto loadB = [&](int kt, short8 (&bf)[4]) {
    #pragma unroll
    for (int ni = 0; ni < 4; ++ni)
      bf[ni] = *(const short8*)(gBb + (size_t)kt * 4096 + ni * 512);
  };

  // ---- A fragment read offsets (u16 elements) ----
  int oct = (((r & 1) << 2) + q) ^ ((r >> 1) & 7);
  int aoff[4];
  #pragma unroll
  for (int x = 0; x < 4; ++x)
    aoff[x] = (wm * 32 + x * 8 + (r >> 1)) * 64 + oct * 8;

  short8 af[4], bfA[4], bfB[4];
  auto preloadA = [&](int sl) {
    #pragma unroll
    for (int x = 0; x < 4; ++x) af[x] = *(const short8*)(&As[sl][aoff[x]]);
  };
  auto burst = [&](short8 (&bf)[4]) {
    #pragma unroll
    for (int ni = 0; ni < 4; ++ni)
      #pragma unroll
      for (int mi = 0; mi < 4; ++mi)
        acc[mi][ni] = __builtin_amdgcn_mfma_f32_16x16x32_bf16(af[mi], bf[ni], acc[mi][ni], 0, 0, 0);
  };

  // prologue: A(KT0..KT0+2) staged into slots 0,1,2; B(KT0),B(KT0+1) in regs.
  // issue order: A0, B0, A1, B1, A2 -> drain A0+B0 with vmcnt(8).
  stageA(KT0, 0);
  loadB(KT0, bfA);
  stageA(KT0 + 1, 1);
  loadB(KT0 + 1, bfB);
  stageA(KT0 + 2, 2);
  __builtin_amdgcn_s_waitcnt(VMCNT_IMM(8));
  __builtin_amdgcn_s_barrier();
  preloadA(0);

  #pragma unroll 1
  for (int kt = KT0; kt < KT1; kt += 2) {
    int j = kt - KT0;                             // ring phase (even)
    int s0 = j % 3, s1 = (j + 1) % 3, s2 = (j + 2) % 3;
    // ---- even step kt: af=A(kt), bfA=B(kt) ----
    burst(bfA);
    if (kt < KT1 - 2) __builtin_amdgcn_s_waitcnt(VMCNT_IMM(6));   // certify A(kt+1)
    else              __builtin_amdgcn_s_waitcnt(VMCNT_IMM(0));
    __builtin_amdgcn_s_barrier();                 // all waves: A(kt+1) landed; slot s0 regs-consumed
    if (kt + 2 < KT1) loadB(kt + 2, bfA);
    if (kt + 3 < KT1) stageA(kt + 3, s0);         // slot s0 free (A(kt) in regs everywhere)
    if (kt + 1 < KT1) preloadA(s1);               // af <- A(kt+1)
    // ---- odd step kt+1: af=A(kt+1), bfB=B(kt+1) ----
    burst(bfB);
    if (kt + 1 < KT1 - 2) __builtin_amdgcn_s_waitcnt(VMCNT_IMM(6));   // certify A(kt+2)
    else                  __builtin_amdgcn_s_waitcnt(VMCNT_IMM(0));
    __builtin_amdgcn_s_barrier();
    if (kt + 3 < KT1) loadB(kt + 3, bfB);
    if (kt + 4 < KT1) stageA(kt + 4, s1);
    if (kt + 2 < KT1) preloadA(s2);               // af <- A(kt+2)
  }

  if (EPI == 2) {
    float* Cfk = Cf + (size_t)ks * YSLICE;
    #pragma unroll
    for (int mi = 0; mi < 4; ++mi) {
      int rowb = m0 + wm * 64 + mi * 16 + q * 4;
      #pragma unroll
      for (int ni = 0; ni < 4; ++ni) {
        int col = n0 + wn * 64 + ni * 16 + r;
        #pragma unroll
        for (int e = 0; e < 4; ++e)
          Cfk[(size_t)(rowb + e) * HD + col] = acc[mi][ni][e];
      }
    }
  } else if (EPI == 0) {
    #pragma unroll
    for (int mi = 0; mi < 4; ++mi) {
      int rowb = m0 + wm * 64 + mi * 16 + q * 4;
      #pragma unroll
      for (int ni = 0; ni < 4; ++ni) {
        int col = n0 + wn * 64 + ni * 16 + r;
        float bcol = bias[col];
        #pragma unroll
        for (int e = 0; e < 4; ++e) {
          float v = acc[mi][ni][e] + bcol;
          v = v > 0.f ? v : 0.f;
          C[(size_t)(rowb + e) * HD + col] = f2bu(v);
        }
      }
    }
  } else {
    float bcol[4], s0c[4], s1c[4], s2c[4], wsc[4];
    #pragma unroll
    for (int ni = 0; ni < 4; ++ni) {
      int col = n0 + wn * 64 + ni * 16 + r;
      bcol[ni] = bias[col]; s0c[ni] = S0[col]; s1c[ni] = S1v[col];
      s2c[ni] = S2v[col];  wsc[ni] = Ws2[col];
    }
    #pragma unroll
    for (int mi = 0; mi < 4; ++mi) {
      int rowb = m0 + wm * 64 + mi * 16 + q * 4;
      #pragma unroll
      for (int e = 0; e < 4; ++e) {
        int row = rowb + e;
        float fi = (float)spI[row];
        float fe = (float)spE[row];
        float fl = fe - fi;
        float p = 0.f;
        #pragma unroll
        for (int ni = 0; ni < 4; ++ni) {
          float v = acc[mi][ni][e] + bcol[ni] + fl * s0c[ni] + fi * s1c[ni] + fe * s2c[ni];
          v = v > 0.f ? v : 0.f;
          p += v * wsc[ni];
        }
        p += __shfl_xor(p, 1);
        p += __shfl_xor(p, 2);
        p += __shfl_xor(p, 4);
        p += __shfl_xor(p, 8);
        if (r == 0 && row < SPANS) atomicAdd(&scores[row], p);
      }
    }
  }
}

extern "C" void kernel_launch(void* const* d_in, const int* in_sizes, int n_in,
                              void* d_out, int out_size, void* d_ws, size_t ws_size,
                              hipStream_t stream) {
  const int*   sent = (const int*)d_in[0];
  const int*   pos  = (const int*)d_in[1];
  const float* Wwrd = (const float*)d_in[2];
  const float* Wpos = (const float*)d_in[3];
  const float* Wd1  = (const float*)d_in[4];
  const float* bd1  = (const float*)d_in[5];
  const float* Wd2  = (const float*)d_in[6];
  const float* bd2  = (const float*)d_in[7];
  const float* Ws1  = (const float*)d_in[8];
  const float* bs1  = (const float*)d_in[9];
  const float* Ws2  = (const float*)d_in[10];
  const float* bs2  = (const float*)d_in[11];
  float* scores = (float*)d_out;

  char* w = (char*)d_ws;
  size_t o = 0;
  auto alloc = [&](size_t bytes) {
    char* p = w + o;
    o = (o + bytes + 255) & ~(size_t)255;
    return p;
  };
  int*   spI   = (int*)  alloc((size_t)MPAD * 4);
  int*   spE   = (int*)  alloc((size_t)MPAD * 4);
  float* spInv = (float*)alloc((size_t)MPAD * 4);
  float* S0    = (float*)alloc(4096);
  float* S1v   = (float*)alloc(4096);
  float* S2v   = (float*)alloc(4096);
  u16*   embB  = (u16*)  alloc((size_t)NTOK * HD * 2);
  float* Ybuf  = (float*)alloc(4 * YSLICE * 4);      // 4 split-K partials
  float* Qp    = (float*)alloc((size_t)(NTOK + 1) * HD * 4);
  u16* Wd1t = (u16*)alloc((size_t)HD * HD * 2);
  u16* Wd2t = (u16*)alloc((size_t)HD * HD * 2);
  u16* Ws1t = (u16*)alloc((size_t)HD * HD * 2);
  u16* Wd1f = (u16*)alloc((size_t)HD * HD * 2);      // fragment-major B buffers
  u16* Wd2f = (u16*)alloc((size_t)HD * HD * 2);
  u16* Ws1f = (u16*)alloc((size_t)HD * HD * 2);
  u16* bufA = (u16*)alloc((size_t)MPAD * HD * 2);
  u16* bufB = (u16*)alloc((size_t)MPAD * HD * 2);

  // fused prep: castT | emb_gather | spans+scores-init | svec
  prep_misc<<<3072 + NTOK + 292 + 4, 256, 0, stream>>>(
      sent, pos, Wwrd, Wpos, embB,
      spI, spE, spInv, scores, bs2,
      Wd1, Wd2, Ws1, Wd1t, Wd2t, Ws1t,
      S0, S1v, S2v);
  // reshuffle B^T -> fragment-major
  bfrag<<<3072, 256, 0, stream>>>(Wd1t, Wd2t, Ws1t, Wd1f, Wd2f, Ws1f);

  // Y = emb @ Wd1  (384x1024x1024, split-K x4 -> 96 blocks, fp32 partials)
  gemm_bt<2><<<96, 256, 0, stream>>>(embB, Wd1f, nullptr, nullptr, Ybuf,
                                     nullptr, nullptr, nullptr, nullptr, nullptr,
                                     nullptr, nullptr);
  yscan<<<HD, NTOK, 0, stream>>>(Ybuf, Qp);
  expand<<<MPAD / 2, 256, 0, stream>>>(Qp, spI, spE, spInv, bd1, bufA);

  gemm_bt<0><<<MTILES * 8, 256, 0, stream>>>(bufA, Wd2f, bd2, bufB, nullptr,
                                             nullptr, nullptr, nullptr, nullptr, nullptr,
                                             nullptr, nullptr);
  gemm_bt<1><<<MTILES * 8, 256, 0, stream>>>(bufB, Ws1f, bs1, nullptr, nullptr,
                                             spI, spE, S0, S1v, S2v, Ws2, scores);
}

// Round 12
// 567.589 us; speedup vs baseline: 1.1849x; 1.0178x over previous
//
#include <hip/hip_runtime.h>

#define NTOK  384
#define SPANS 73920          // 384*385/2
#define MTILES 584           // 73*8 so grid=584*8 maps cleanly onto 8 XCDs
#define MPAD  (MTILES * 128) // 74752
#define HD    1024
#define BK    32
#define KTS   (HD / BK)      // 32
#define YSLICE ((size_t)NTOK * HD)

typedef unsigned short u16;
typedef __attribute__((ext_vector_type(8))) short short8;
typedef __attribute__((ext_vector_type(4))) float floatx4;

// gfx9 s_waitcnt immediate: vmcnt[3:0]|[15:14], expcnt[6:4], lgkmcnt[11:8]
#define VMCNT_IMM(N) (((N) & 0xF) | (((N) >> 4) << 14) | (0x7 << 4) | (0xF << 8))

__device__ __forceinline__ u16 f2bu(float x) {
  union { float f; unsigned u; } un; un.f = x;
  unsigned r = un.u + 0x7fffu + ((un.u >> 16) & 1u);   // RNE
  return (u16)(r >> 16);
}

__device__ __forceinline__ void gld_lds16(const void* g, void* l) {
  __builtin_amdgcn_global_load_lds(
      (const __attribute__((address_space(1))) void*)g,
      (__attribute__((address_space(3))) void*)l, 16, 0, 0);
}

// ---- fused prep: castT->FRAGMENT-MAJOR (3072 blocks) | emb_gather (384) | spans (292) | svec (4)
// Round-12: castT writes the fragment-major B layout directly (bfrag folded in,
// row-major intermediates eliminated). Fragment addr for Bt[n][k]:
//   nt=n>>7, wn=(n>>6)&1, ni=(n>>4)&3, r=n&15, kt=k>>5, q=(k>>3)&3, u=k&7
//   addr = nt*131072 + kt*4096 + wn*2048 + ni*512 + (q*16+r)*8 + u
// (verified identical to the R9/R10/R11 bfrag map; kt=tk and q=(x>>3)&3 because
// k0=tk*32 is 32-aligned).
__global__ void prep_misc(const int* __restrict__ sent, const int* __restrict__ pos,
                          const float* __restrict__ Wwrd, const float* __restrict__ Wpos,
                          u16* __restrict__ embB,
                          int* __restrict__ spI, int* __restrict__ spE, float* __restrict__ spInv,
                          float* __restrict__ scores, const float* __restrict__ bs2,
                          const float* __restrict__ Wd1, const float* __restrict__ Wd2,
                          const float* __restrict__ Ws1,
                          u16* __restrict__ f1, u16* __restrict__ f2, u16* __restrict__ f3,
                          float* __restrict__ S0, float* __restrict__ S1v, float* __restrict__ S2v) {
  __shared__ u16 tile[32][33];
  int bx = blockIdx.x;
  if (bx < 3072) {
    // transpose+cast one 32x32 block of a 1024x1024 weight to bf16 fragment-major
    int w = bx >> 10, rem = bx & 1023;
    int tk = rem >> 5, tn = rem & 31;
    const float* src = (w == 0) ? Wd1 : ((w == 1) ? Wd2 : Ws1);
    u16* dst = (w == 0) ? f1 : ((w == 1) ? f2 : f3);
    int x = threadIdx.x & 31, y = threadIdx.x >> 5;   // y in 0..7
    int k0 = tk * 32, n0 = tn * 32;
    for (int yy = 0; yy < 32; yy += 8)
      tile[y + yy][x] = f2bu(src[(size_t)(k0 + y + yy) * HD + n0 + x]);
    __syncthreads();
    // write: element Bt[n][k] = W[k][n], n = n0+y+yy, k = k0+x
    int qq = (x >> 3) & 3, u = x & 7;
    size_t kbase = (size_t)tk * 4096 + (size_t)qq * 128 + u;   // (q*16)*8 = q*128
    for (int yy = 0; yy < 32; yy += 8) {
      int n = n0 + y + yy;
      int nt2 = n >> 7, wn2 = (n >> 6) & 1, ni2 = (n >> 4) & 3, rr = n & 15;
      dst[(size_t)nt2 * 131072 + kbase + wn2 * 2048 + ni2 * 512 + rr * 8] = tile[x][y + yy];
    }
  } else if (bx < 3072 + NTOK) {
    // gather token embeddings as bf16 [384][1024]
    int t = bx - 3072;
    int c = threadIdx.x;
    int pt = pos[t], st = sent[t];
    #pragma unroll
    for (int u = 0; u < 4; ++u) {
      int col = u * 256 + c;
      float v = (col < 512) ? Wpos[(size_t)pt * 512 + col]
                            : Wwrd[(size_t)st * 512 + (col - 512)];
      embB[(size_t)t * HD + col] = f2bu(v);
    }
  } else if (bx < 3072 + NTOK + 292) {
    // span (i, end, 1/len) + scores init
    int rf = (bx - 3072 - NTOK) * 256 + threadIdx.x;
    if (rf >= MPAD) return;
    int s = rf < SPANS ? rf : SPANS - 1;
    const int n = NTOK;
    double tn2 = 2.0 * n + 1.0;
    int i = (int)((tn2 - sqrt(tn2 * tn2 - 8.0 * (double)s)) * 0.5);
    if (i < 0) i = 0;
    if (i > n - 1) i = n - 1;
    #define OFF(ii) (((ii) * (2 * n - (ii) + 1)) / 2)
    while (i + 1 <= n - 1 && OFF(i + 1) <= s) ++i;
    while (i > 0 && OFF(i) > s) --i;
    int j = i + (s - OFF(i));
    #undef OFF
    spI[rf] = i;
    spE[rf] = j + 1;
    spInv[rf] = 1.0f / (float)(j + 1 - i);
    if (rf < SPANS) scores[rf] = bs2[0];
  } else {
    // S0/S1/S2 = column sums of W_s1's feat rows (len/start/end, 16 each)
    int c = (bx - 3072 - NTOK - 292) * 256 + threadIdx.x;
    if (c >= HD) return;
    float a = 0.f, b = 0.f, d = 0.f;
    for (int r = 0; r < 16; ++r) {
      a += Ws1[(size_t)(1024 + r) * HD + c];
      b += Ws1[(size_t)(1040 + r) * HD + c];
      d += Ws1[(size_t)(1056 + r) * HD + c];
    }
    S0[c] = a; S1v[c] = b; S2v[c] = d;
  }
}

// ---- Qp = [0; cumsum(sum of 4 K-partials, rows)] fp32, per-column parallel scan ----
__global__ void yscan(const float* __restrict__ Y, float* __restrict__ Qp) {
  __shared__ float buf[NTOK];
  int c = blockIdx.x;           // 0..1023
  int t = threadIdx.x;          // 0..383
  size_t idx = (size_t)t * HD + c;
  buf[t] = Y[idx] + Y[idx + YSLICE] + Y[idx + 2 * YSLICE] + Y[idx + 3 * YSLICE];
  __syncthreads();
  #pragma unroll
  for (int off = 1; off < NTOK; off <<= 1) {
    float add = (t >= off) ? buf[t - off] : 0.f;
    __syncthreads();
    buf[t] += add;
    __syncthreads();
  }
  if (t == 0) Qp[c] = 0.f;
  Qp[(size_t)(t + 1) * HD + c] = buf[t];
}

// ---- expand: h1[s] = relu((Qp[e]-Qp[i])*inv + b1) -> bf16 [MPAD][1024] (row-major) ----
__global__ void expand(const float* __restrict__ Qp, const int* __restrict__ spI,
                       const int* __restrict__ spE, const float* __restrict__ spInv,
                       const float* __restrict__ b1, u16* __restrict__ out) {
  int gid = blockIdx.x * 256 + threadIdx.x;   // MPAD*128 threads
  int row = gid >> 7;
  int c0 = (gid & 127) << 3;
  int i = spI[row], e = spE[row];
  float inv = spInv[row];
  const float* pe = Qp + (size_t)e * HD + c0;
  const float* pi = Qp + (size_t)i * HD + c0;
  const float* bb = b1 + c0;
  u16 tmp[8];
  #pragma unroll
  for (int u = 0; u < 8; ++u) {
    float v = (pe[u] - pi[u]) * inv + bb[u];
    v = v > 0.f ? v : 0.f;
    tmp[u] = f2bu(v);
  }
  *(uint4*)(out + (size_t)row * HD + c0) = *(const uint4*)tmp;
}

// ---- GEMM: C[M,1024] = A[M,1024] @ B^T (+ bias, relu)  [R9-verified best]
// 128x128 tile, 4 waves, BK=32; A via gld_lds stripe staging (0-conflict),
// B direct from fragment-major global (L2-resident, coalesced 1KB/instr) into
// named double-buffered registers; single barrier + vmcnt(0) per K-step.
// EPI==0: relu+bias, store bf16 C (row-major).
// EPI==1: + feats affine, relu, dot W_s2, shfl reduce, atomicAdd scores.
// EPI==2: plain fp32 store, split-K x4 (grid 96, 8 K-steps each).
template <int EPI>
__global__ __launch_bounds__(256, 4) void gemm_bt(
    const u16* __restrict__ A, const u16* __restrict__ Bf,
    const float* __restrict__ bias, u16* __restrict__ C, float* __restrict__ Cf,
    const int* __restrict__ spI, const int* __restrict__ spE,
    const float* __restrict__ S0, const float* __restrict__ S1v, const float* __restrict__ S2v,
    const float* __restrict__ Ws2, float* __restrict__ scores) {
  __shared__ u16 As[2][128 * BK];   // 8 KB per slot; A only
  int bx = blockIdx.x;
  int mt, nt, ks = 0, KT0 = 0, KT1 = KTS;
  if (EPI == 2) {
    int rem = bx & 31;
    nt = rem & 7; ks = rem >> 3; mt = bx >> 5;     // grid 96 = 3mt x 8nt x 4ks
    KT0 = ks * 8; KT1 = KT0 + 8;
  } else {
    int xcd = bx & 7, k = bx >> 3;
    nt = k & 7;
    mt = xcd + 8 * (k >> 3);        // mt%8 == xcd; blocks per XCD share mt (A L2 reuse)
  }
  int m0 = mt * 128;
  int n0 = nt * 128;
  int t = threadIdx.x, lane = t & 63, wid = t >> 6;
  int wm = wid >> 1, wn = wid & 1;
  int q = lane >> 4, r = lane & 15;

  floatx4 acc[4][4] = {};

  // ---- A staging geometry (verified stripe swizzle; one DMA op = 16 rows x 64B) ----
  int dsub = (lane & 7) ^ ((lane >> 3) & 7);
  int row0 = wid * 16 + 2 * (lane >> 3) + (dsub >> 2);
  int voff = row0 * HD + (dsub & 3) * 8;          // u16 elems; kt-invariant
  const u16* gA0 = A + (size_t)m0 * HD;
  int ldsOff0 = wid * 512;                        // u16; wave-uniform dests
  int ldsOff1 = 2048 + wid * 512;                 // +64 rows = +32 stripes

  auto stageA = [&](int kt, int b) {
    const u16* pa = gA0 + voff + kt * BK;
    gld_lds16(pa,                   &As[b][ldsOff0]);
    gld_lds16(pa + (size_t)64 * HD, &As[b][ldsOff1]);
  };

  // ---- B fragment-major base (u16 units): nt*131072 + kt*4096 + wn*2048 + ni*512 + lane*8 ----
  const u16* gBb = Bf + (size_t)nt * 131072 + wn * 2048 + lane * 8;
  auto loadB = [&](int kt, short8 (&bf)[4]) {
    #pragma unroll
    for (int ni = 0; ni < 4; ++ni)
      bf[ni] = *(const short8*)(gBb + (size_t)kt * 4096 + ni * 512);
  };

  // ---- A fragment read offsets (u16 elements) ----
  int oct = (((r & 1) << 2) + q) ^ ((r >> 1) & 7);
  int aoff[4];
  #pragma unroll
  for (int x = 0; x < 4; ++x)
    aoff[x] = (wm * 32 + x * 8 + (r >> 1)) * 64 + oct * 8;

  short8 af[4], bfA[4], bfB[4];
  auto preloadA = [&](int b) {
    #pragma unroll
    for (int x = 0; x < 4; ++x) af[x] = *(const short8*)(&As[b][aoff[x]]);
  };
  auto burst = [&](short8 (&bf)[4]) {
    #pragma unroll
    for (int ni = 0; ni < 4; ++ni)
      #pragma unroll
      for (int mi = 0; mi < 4; ++mi)
        acc[mi][ni] = __builtin_amdgcn_mfma_f32_16x16x32_bf16(af[mi], bf[ni], acc[mi][ni], 0, 0, 0);
  };

  // prologue: A(KT0),A(KT0+1) staged; B(KT0),B(KT0+1) in regs; certify KT0
  stageA(KT0, 0);
  stageA(KT0 + 1, 1);
  loadB(KT0, bfA);
  loadB(KT0 + 1, bfB);
  __builtin_amdgcn_s_waitcnt(VMCNT_IMM(0));
  __builtin_amdgcn_s_barrier();
  preloadA(0);

  #pragma unroll 1
  for (int kt = KT0; kt < KT1; kt += 2) {
    // ---- even step: af=A(kt), bfA=B(kt) ----
    burst(bfA);
    __builtin_amdgcn_s_waitcnt(VMCNT_IMM(0));     // A(kt+1) staged + B in flight drained
    __builtin_amdgcn_s_barrier();                 // A(kt+1) visible; slot 0 consumed by all
    if (kt + 2 < KT1) { stageA(kt + 2, 0); loadB(kt + 2, bfA); }
    preloadA(1);                                  // af <- A(kt+1)
    // ---- odd step: af=A(kt+1), bfB=B(kt+1) ----
    burst(bfB);
    __builtin_amdgcn_s_waitcnt(VMCNT_IMM(0));
    __builtin_amdgcn_s_barrier();
    if (kt + 3 < KT1) { stageA(kt + 3, 1); loadB(kt + 3, bfB); }
    if (kt + 2 < KT1) preloadA(0);
  }

  if (EPI == 2) {
    float* Cfk = Cf + (size_t)ks * YSLICE;
    #pragma unroll
    for (int mi = 0; mi < 4; ++mi) {
      int rowb = m0 + wm * 64 + mi * 16 + q * 4;
      #pragma unroll
      for (int ni = 0; ni < 4; ++ni) {
        int col = n0 + wn * 64 + ni * 16 + r;
        #pragma unroll
        for (int e = 0; e < 4; ++e)
          Cfk[(size_t)(rowb + e) * HD + col] = acc[mi][ni][e];
      }
    }
  } else if (EPI == 0) {
    #pragma unroll
    for (int mi = 0; mi < 4; ++mi) {
      int rowb = m0 + wm * 64 + mi * 16 + q * 4;
      #pragma unroll
      for (int ni = 0; ni < 4; ++ni) {
        int col = n0 + wn * 64 + ni * 16 + r;
        float bcol = bias[col];
        #pragma unroll
        for (int e = 0; e < 4; ++e) {
          float v = acc[mi][ni][e] + bcol;
          v = v > 0.f ? v : 0.f;
          C[(size_t)(rowb + e) * HD + col] = f2bu(v);
        }
      }
    }
  } else {
    float bcol[4], s0c[4], s1c[4], s2c[4], wsc[4];
    #pragma unroll
    for (int ni = 0; ni < 4; ++ni) {
      int col = n0 + wn * 64 + ni * 16 + r;
      bcol[ni] = bias[col]; s0c[ni] = S0[col]; s1c[ni] = S1v[col];
      s2c[ni] = S2v[col];  wsc[ni] = Ws2[col];
    }
    #pragma unroll
    for (int mi = 0; mi < 4; ++mi) {
      int rowb = m0 + wm * 64 + mi * 16 + q * 4;
      #pragma unroll
      for (int e = 0; e < 4; ++e) {
        int row = rowb + e;
        float fi = (float)spI[row];
        float fe = (float)spE[row];
        float fl = fe - fi;
        float p = 0.f;
        #pragma unroll
        for (int ni = 0; ni < 4; ++ni) {
          float v = acc[mi][ni][e] + bcol[ni] + fl * s0c[ni] + fi * s1c[ni] + fe * s2c[ni];
          v = v > 0.f ? v : 0.f;
          p += v * wsc[ni];
        }
        p += __shfl_xor(p, 1);
        p += __shfl_xor(p, 2);
        p += __shfl_xor(p, 4);
        p += __shfl_xor(p, 8);
        if (r == 0 && row < SPANS) atomicAdd(&scores[row], p);
      }
    }
  }
}

extern "C" void kernel_launch(void* const* d_in, const int* in_sizes, int n_in,
                              void* d_out, int out_size, void* d_ws, size_t ws_size,
                              hipStream_t stream) {
  const int*   sent = (const int*)d_in[0];
  const int*   pos  = (const int*)d_in[1];
  const float* Wwrd = (const float*)d_in[2];
  const float* Wpos = (const float*)d_in[3];
  const float* Wd1  = (const float*)d_in[4];
  const float* bd1  = (const float*)d_in[5];
  const float* Wd2  = (const float*)d_in[6];
  const float* bd2  = (const float*)d_in[7];
  const float* Ws1  = (const float*)d_in[8];
  const float* bs1  = (const float*)d_in[9];
  const float* Ws2  = (const float*)d_in[10];
  const float* bs2  = (const float*)d_in[11];
  float* scores = (float*)d_out;

  char* w = (char*)d_ws;
  size_t o = 0;
  auto alloc = [&](size_t bytes) {
    char* p = w + o;
    o = (o + bytes + 255) & ~(size_t)255;
    return p;
  };
  int*   spI   = (int*)  alloc((size_t)MPAD * 4);
  int*   spE   = (int*)  alloc((size_t)MPAD * 4);
  float* spInv = (float*)alloc((size_t)MPAD * 4);
  float* S0    = (float*)alloc(4096);
  float* S1v   = (float*)alloc(4096);
  float* S2v   = (float*)alloc(4096);
  u16*   embB  = (u16*)  alloc((size_t)NTOK * HD * 2);
  float* Ybuf  = (float*)alloc(4 * YSLICE * 4);      // 4 split-K partials
  float* Qp    = (float*)alloc((size_t)(NTOK + 1) * HD * 4);
  u16* Wd1f = (u16*)alloc((size_t)HD * HD * 2);      // fragment-major B buffers
  u16* Wd2f = (u16*)alloc((size_t)HD * HD * 2);
  u16* Ws1f = (u16*)alloc((size_t)HD * HD * 2);
  u16* bufA = (u16*)alloc((size_t)MPAD * HD * 2);
  u16* bufB = (u16*)alloc((size_t)MPAD * HD * 2);

  // fused prep: castT->fragment-major | emb_gather | spans+scores-init | svec
  prep_misc<<<3072 + NTOK + 292 + 4, 256, 0, stream>>>(
      sent, pos, Wwrd, Wpos, embB,
      spI, spE, spInv, scores, bs2,
      Wd1, Wd2, Ws1, Wd1f, Wd2f, Ws1f,
      S0, S1v, S2v);

  // Y = emb @ Wd1  (384x1024x1024, split-K x4 -> 96 blocks, fp32 partials)
  gemm_bt<2><<<96, 256, 0, stream>>>(embB, Wd1f, nullptr, nullptr, Ybuf,
                                     nullptr, nullptr, nullptr, nullptr, nullptr,
                                     nullptr, nullptr);
  yscan<<<HD, NTOK, 0, stream>>>(Ybuf, Qp);
  expand<<<MPAD / 2, 256, 0, stream>>>(Qp, spI, spE, spInv, bd1, bufA);

  gemm_bt<0><<<MTILES * 8, 256, 0, stream>>>(bufA, Wd2f, bd2, bufB, nullptr,
                                             nullptr, nullptr, nullptr, nullptr, nullptr,
                                             nullptr, nullptr);
  gemm_bt<1><<<MTILES * 8, 256, 0, stream>>>(bufB, Ws1f, bs1, nullptr, nullptr,
                                             spI, spE, S0, S1v, S2v, Ws2, scores);
}